// Round 3
// baseline (78.660 us; speedup 1.0000x reference)
//
#include <hip/hip_runtime.h>
#include <hip/hip_bf16.h>
#include <stdint.h>

typedef __attribute__((ext_vector_type(4))) float f32x4;
typedef __attribute__((ext_vector_type(4))) unsigned int u32x4;
typedef __attribute__((ext_vector_type(8))) short short8;

#define MFMA16(a, b, c) __builtin_amdgcn_mfma_f32_16x16x32_bf16((a), (b), (c), 0, 0, 0)

__device__ __forceinline__ uint16_t f2bf(float f) {
  __hip_bfloat16 h = __float2bfloat16(f);
  return __builtin_bit_cast(uint16_t, h);
}

// v_rcp_f32-based sigmoid: rcp rel-err ~1ulp << bf16 rounding of every consumer.
__device__ __forceinline__ float fast_sigmoid(float v) {
  return __builtin_amdgcn_rcpf(1.f + __expf(-v));
}

__device__ __forceinline__ short8 cvt8(f32x4 a, f32x4 b) {
  short8 r;
  r[0] = (short)f2bf(a[0]); r[1] = (short)f2bf(a[1]);
  r[2] = (short)f2bf(a[2]); r[3] = (short)f2bf(a[3]);
  r[4] = (short)f2bf(b[0]); r[5] = (short)f2bf(b[1]);
  r[6] = (short)f2bf(b[2]); r[7] = (short)f2bf(b[3]);
  return r;
}

// XOR-swizzled byte offset into row-major [rows][RB bytes] LDS tile (16B slots).
template <int RB>
__device__ __forceinline__ int swzoff(int row, int bcol) {
  constexpr int SLM = (((RB / 16) < 8 ? (RB / 16) : 8)) - 1;
  return row * RB + (bcol ^ ((row & SLM) << 4));
}

// A-fragment (16x32 bf16) from swizzled bf16 LDS tile.
template <int RB>
__device__ __forceinline__ short8 lds_a(const uint16_t* buf, int row0, int k0, int lane) {
  int r = row0 + (lane & 15);
  int bcol = (k0 + ((lane >> 4) << 3)) * 2;
  u32x4 raw = *(const u32x4*)((const char*)buf + swzoff<RB>(r, bcol));
  return __builtin_bit_cast(short8, raw);
}

// A-fragment (16x32 bf16) from the 80B-pitched L1 staging tile.
// pitch 80 = 5*16B: slot-group (5r+s) mod 8 spreads 16 rows x 4 slots evenly
// over all 8 LDS bank-groups -> conflict-free b128 without XOR swizzle.
__device__ __forceinline__ short8 lds_a_s(const char* sb, int row0, int lane) {
  int r = row0 + (lane & 15);
  return *(const short8*)(sb + r * 80 + ((lane >> 4) << 4));
}

// Fragment from row-major fp32 M[ld] (coalesced 16-row pattern)
__device__ __forceinline__ short8 load_frag_f32(const float* M, int ld, int r0, int k0, int lane) {
  const float* p = M + (size_t)(r0 + (lane & 15)) * ld + (k0 + ((lane >> 4) << 3));
  f32x4 a = *(const f32x4*)p;
  f32x4 b = *(const f32x4*)(p + 4);
  return cvt8(a, b);
}

// Packed-path B-fragment: one coalesced 16B load from pre-packed d_ws
__device__ __forceinline__ short8 load_b_pk(const char* base, int f, int lane) {
  u32x4 raw = *(const u32x4*)(base + (((size_t)f * 64 + lane) << 4));
  return __builtin_bit_cast(short8, raw);
}

template <bool P>
__device__ __forceinline__ short8 bfrag(const char* wp, const float* W, int K,
                                        int f0, int ntg, int KT, int kt, int lane) {
  if constexpr (P) {
    return load_b_pk(wp, f0 + ntg * KT + kt, lane);
  } else {
    return load_frag_f32(W, K, ntg * 16, kt * 32, lane);
  }
}

// ---- weight pre-pack: 372 fragments x (64 lanes x 16B) = 372 KB in d_ws ----
__global__ void pack_kernel(const float* __restrict__ w1, const float* __restrict__ w2,
                            const float* __restrict__ w3, const float* __restrict__ w4,
                            const float* __restrict__ w5, char* __restrict__ ws) {
  int b = blockIdx.x, lane = threadIdx.x;
  const float* W;
  int K, f0;
  if (b < 256)      { W = w1; K = 512; f0 = 0; }
  else if (b < 320) { W = w2; K = 256; f0 = 256; }
  else if (b < 336) { W = w3; K = 128; f0 = 320; }
  else if (b < 340) { W = w4; K = 64;  f0 = 336; }
  else              { W = w5; K = 32;  f0 = 340; }
  int f = b - f0;
  int KT = K / 32;
  int nt = f / KT, kt = f % KT;
  short8 r = load_frag_f32(W, K, nt * 16, kt * 32, lane);
  *(u32x4*)(ws + (((size_t)b * 64 + lane) << 4)) = __builtin_bit_cast(u32x4, r);
}

// Non-draining chunk barrier: drain LDS ops only; VMEM prefetches stay in flight.
// sched_barrier(0) fences instruction motion across the barrier (rule #18).
#define CHUNK_BAR()                                           \
  asm volatile("s_waitcnt lgkmcnt(0)" ::: "memory");          \
  __builtin_amdgcn_s_barrier();                               \
  __builtin_amdgcn_sched_barrier(0);

// One L1 K-chunk, fully register-carried pipeline (compiler derives counted
// vmcnt automatically — no global_load_lds, no manual vmcnt):
//   chunk k's x-rows: global->rA[k&1] at step k-2; cvt+ds_write at step k-1;
//   consumed (4 ds_read_b128 + 16 MFMA, zero cvt on critical path) at step k.
//   B frags: bfr[k&1] loaded at step k-1.
#define KSTEP(C)                                                              \
  {                                                                           \
    CHUNK_BAR();                                                              \
    if ((C) + 2 < 16) {                                                       \
      const float* p = xrow + ((C) + 2) * 32;                                 \
      rA[(C) & 1][0] = *(const f32x4*)p;                                      \
      rA[(C) & 1][1] = *(const f32x4*)(p + 4);                                \
    }                                                                         \
    if ((C) + 1 < 16) {                                                       \
      _Pragma("unroll") for (int nt = 0; nt < 4; ++nt)                        \
          bfr[((C) + 1) & 1][nt] =                                            \
              bfrag<P>(wp, w1, 512, 0, wid * 4 + nt, 16, (C) + 1, lane);      \
    }                                                                         \
    __builtin_amdgcn_sched_barrier(0);                                        \
    if ((C) + 1 < 16) {                                                       \
      short8 wv = cvt8(rA[((C) + 1) & 1][0], rA[((C) + 1) & 1][1]);           \
      *(short8*)(sring + (((C) + 1) & 1) * 5120 + swb) = wv;                  \
    }                                                                         \
    const char* sc = sring + ((C) & 1) * 5120;                                \
    _Pragma("unroll") for (int m = 0; m < 4; ++m) {                           \
      short8 a = lds_a_s(sc, m * 16, lane);                                   \
      _Pragma("unroll") for (int nt = 0; nt < 4; ++nt)                        \
          acc[m][nt] = MFMA16(a, bfr[(C) & 1][nt], acc[m][nt]);               \
    }                                                                         \
  }

// 64 rows/block, 256 threads, 32KB arena, (256,3): VGPR cap 168 (no spill;
// (256,4)'s 128-cap spilled ~100MB scratch in round 1).
template <bool P>
__global__ __launch_bounds__(256, 3) void mlp5_kernel(
    const float* __restrict__ x,
    const float* __restrict__ w1, const float* __restrict__ b1,
    const float* __restrict__ w2, const float* __restrict__ b2,
    const float* __restrict__ w3, const float* __restrict__ b3,
    const float* __restrict__ w4, const float* __restrict__ b4,
    const float* __restrict__ w5, const float* __restrict__ b5,
    const char* __restrict__ wp, float* __restrict__ out) {
  // Arena 32KB (every overlay is protected by an existing barrier):
  //   L1: S ring [0,10240) = 2 x 5120B bf16 chunks (80B pitch, reg-staged)
  //   L1 epilogue (after syncthreads): H1 [0,32K) overlays ring
  //   L2: H1 in; H2 [0,16K) out (after the barrier following last H1 read)
  //   L3: H2 in, H3 [16K,24K) out
  //   L4: H3 in, H4 [24K,28K) out
  //   L5: H4 in
  __shared__ __align__(16) char smem[32 * 1024];
  uint16_t* H1 = (uint16_t*)smem;                // [64][256] bf16, RB=512
  uint16_t* H2 = (uint16_t*)smem;                // [64][128] bf16, RB=256
  uint16_t* H3 = (uint16_t*)(smem + 16 * 1024);  // [64][64]  bf16, RB=128
  uint16_t* H4 = (uint16_t*)(smem + 24 * 1024);  // [64][32]  bf16, RB=64

  const int tid = threadIdx.x;
  const int lane = tid & 63;
  const int wid = tid >> 6;
  const int row0 = blockIdx.x * 64;
  const int lr = (lane >> 4) << 2;
  const int lc = lane & 15;

  // in_size = count_nonzero(x[0])
  int in_size = 0;
#pragma unroll
  for (int j = 0; j < 8; ++j) {
    float v = x[j * 64 + lane];
    in_size += (int)__popcll(__ballot(v != 0.f));
  }

  // ---- Layer 1: x[64x512] @ w1[256x512]^T -> h1[64x256]
  // Each wave stages its own 16 rows: global->reg (2 dwordx4), cvt once,
  // ds_write_b128 bf16 into 80B-pitch tile. Consumers: 4 ds_read_b128/chunk.
  char* sring = smem;
  const float* xrow =
      x + (size_t)(row0 + wid * 16 + (lane & 15)) * 512 + ((lane >> 4) << 3);
  const int swb = (wid * 16 + (lane & 15)) * 80 + ((lane >> 4) << 4);

  f32x4 acc[4][4];
#pragma unroll
  for (int m = 0; m < 4; ++m)
#pragma unroll
    for (int n = 0; n < 4; ++n) acc[m][n] = (f32x4){0.f, 0.f, 0.f, 0.f};

  f32x4 rA[2][2];
  short8 bfr[2][4];
  // Prologue: chunk0 -> rA[0], chunk1 -> rA[1], B(chunk0) -> bfr[0];
  // cvt chunk0 -> LDS slot0 (compiler waits only chunk0's loads).
  rA[0][0] = *(const f32x4*)(xrow + 0);
  rA[0][1] = *(const f32x4*)(xrow + 4);
  rA[1][0] = *(const f32x4*)(xrow + 32);
  rA[1][1] = *(const f32x4*)(xrow + 36);
#pragma unroll
  for (int nt = 0; nt < 4; ++nt)
    bfr[0][nt] = bfrag<P>(wp, w1, 512, 0, wid * 4 + nt, 16, 0, lane);
  {
    short8 wv = cvt8(rA[0][0], rA[0][1]);
    *(short8*)(sring + swb) = wv;
  }

  KSTEP(0)  KSTEP(1)  KSTEP(2)  KSTEP(3)
  KSTEP(4)  KSTEP(5)  KSTEP(6)  KSTEP(7)
  KSTEP(8)  KSTEP(9)  KSTEP(10) KSTEP(11)
  KSTEP(12) KSTEP(13) KSTEP(14) KSTEP(15)

  // Hoist L2's weight fragments (L2$ latency hides under barrier + epilogue VALU)
  short8 bfr2[2][8];
#pragma unroll
  for (int n = 0; n < 2; ++n)
#pragma unroll
    for (int kt = 0; kt < 8; ++kt)
      bfr2[n][kt] = bfrag<P>(wp, w2, 256, 256, wid * 2 + n, 8, kt, lane);

  __syncthreads();  // all S-ring reads done before H1 overlays [0,32K)

  // L1 epilogue: bias + sigmoid -> H1
#pragma unroll
  for (int n = 0; n < 4; ++n) {
    const int ncol = wid * 64 + n * 16;
    const float bv = b1[ncol + lc];
#pragma unroll
    for (int m = 0; m < 4; ++m)
#pragma unroll
      for (int i = 0; i < 4; ++i) {
        float v = fast_sigmoid(acc[m][n][i] + bv);
        *(uint16_t*)((char*)H1 + swzoff<512>(m * 16 + lr + i, (ncol + lc) * 2)) = f2bf(v);
      }
  }
  __syncthreads();

  // ---- Layer 2: h1[64x256] -> h2[64x128]; wave cols wid*32 (2 nt), 4 mt, KT=8
  {
    f32x4 acc2[4][2];
#pragma unroll
    for (int m = 0; m < 4; ++m)
#pragma unroll
      for (int n = 0; n < 2; ++n) acc2[m][n] = (f32x4){0.f, 0.f, 0.f, 0.f};
#pragma unroll
    for (int m = 0; m < 4; ++m) {
#pragma unroll
      for (int kt = 0; kt < 8; ++kt) {
        short8 afr = lds_a<512>(H1, m * 16, kt * 32, lane);
        acc2[m][0] = MFMA16(afr, bfr2[0][kt], acc2[m][0]);
        acc2[m][1] = MFMA16(afr, bfr2[1][kt], acc2[m][1]);
      }
    }
    // Hoist L3 weights
    short8 bfr3[4];
#pragma unroll
    for (int kt = 0; kt < 4; ++kt)
      bfr3[kt] = bfrag<P>(wp, w3, 128, 320, wid, 4, kt, lane);
    __syncthreads();  // REQUIRED: last H1 read done before H2 overlays [0,16K)
#pragma unroll
    for (int n = 0; n < 2; ++n) {
      const int ncol = wid * 32 + n * 16;
      const float bv = b2[ncol + lc];
#pragma unroll
      for (int m = 0; m < 4; ++m)
#pragma unroll
        for (int i = 0; i < 4; ++i) {
          float v = fast_sigmoid(acc2[m][n][i] + bv);
          *(uint16_t*)((char*)H2 + swzoff<256>(m * 16 + lr + i, (ncol + lc) * 2)) = f2bf(v);
        }
    }
    __syncthreads();

    // ---- Layer 3: h2[64x128] -> h3[64x64]; wave col-tile wid (1 nt), 4 mt, KT=4
    f32x4 acc3[4];
#pragma unroll
    for (int m = 0; m < 4; ++m) acc3[m] = (f32x4){0.f, 0.f, 0.f, 0.f};
#pragma unroll
    for (int m = 0; m < 4; ++m)
#pragma unroll
      for (int kt = 0; kt < 4; ++kt) {
        short8 afr = lds_a<256>(H2, m * 16, kt * 32, lane);
        acc3[m] = MFMA16(afr, bfr3[kt], acc3[m]);
      }
    // Hoist L4 weights
    short8 bfr4[2];
#pragma unroll
    for (int kt = 0; kt < 2; ++kt)
      bfr4[kt] = bfrag<P>(wp, w4, 64, 336, wid & 1, 2, kt, lane);
    {
      const int ncol = wid * 16;
      const float bv = b3[ncol + lc];
#pragma unroll
      for (int m = 0; m < 4; ++m)
#pragma unroll
        for (int i = 0; i < 4; ++i) {
          float v = fast_sigmoid(acc3[m][i] + bv);
          *(uint16_t*)((char*)H3 + swzoff<128>(m * 16 + lr + i, (ncol + lc) * 2)) = f2bf(v);
        }
    }
    __syncthreads();

    // ---- Layer 4: h3[64x64] -> h4[64x32]; waves 2x2: rows wm*32 (2 mt), col wn*16, KT=2
    const int wm = wid >> 1, wn = wid & 1;
    f32x4 acc4[2];
#pragma unroll
    for (int mt = 0; mt < 2; ++mt) acc4[mt] = (f32x4){0.f, 0.f, 0.f, 0.f};
#pragma unroll
    for (int mt = 0; mt < 2; ++mt)
#pragma unroll
      for (int kt = 0; kt < 2; ++kt) {
        short8 afr = lds_a<128>(H3, wm * 32 + mt * 16, kt * 32, lane);
        acc4[mt] = MFMA16(afr, bfr4[kt], acc4[mt]);
      }
    // Hoist L5 weights
    short8 bfr5[8];
#pragma unroll
    for (int nt = 0; nt < 8; ++nt)
      bfr5[nt] = bfrag<P>(wp, w5, 32, 340, wid * 8 + nt, 1, 0, lane);
    {
      const int ncol = wn * 16;
      const float bv = b4[ncol + lc];
#pragma unroll
      for (int mt = 0; mt < 2; ++mt)
#pragma unroll
        for (int i = 0; i < 4; ++i) {
          float v = fast_sigmoid(acc4[mt][i] + bv);
          *(uint16_t*)((char*)H4 + swzoff<64>(wm * 32 + mt * 16 + lr + i, (ncol + lc) * 2)) = f2bf(v);
        }
    }
    __syncthreads();

    // ---- Layer 5: h4[64x32] -> out[64x512]; wave cols wid*128 (8 nt), 4 mt, KT=1
#pragma unroll
    for (int m = 0; m < 4; ++m) {
      short8 afr = lds_a<64>(H4, m * 16, 0, lane);
#pragma unroll
      for (int nt = 0; nt < 8; ++nt) {
        f32x4 av = MFMA16(afr, bfr5[nt], ((f32x4){0.f, 0.f, 0.f, 0.f}));
        const int col = wid * 128 + nt * 16 + lc;
        const float bv = b5[col];
        const bool keep = col < in_size;
#pragma unroll
        for (int i = 0; i < 4; ++i) {
          float v = keep ? (av[i] + bv) : 0.f;
          out[(size_t)(row0 + m * 16 + lr + i) * 512 + col] = v;
        }
      }
    }
  }
}

extern "C" void kernel_launch(void* const* d_in, const int* in_sizes, int n_in,
                              void* d_out, int out_size, void* d_ws, size_t ws_size,
                              hipStream_t stream) {
  const float* x  = (const float*)d_in[0];
  const float* w1 = (const float*)d_in[1];
  const float* b1 = (const float*)d_in[2];
  const float* w2 = (const float*)d_in[3];
  const float* b2 = (const float*)d_in[4];
  const float* w3 = (const float*)d_in[5];
  const float* b3 = (const float*)d_in[6];
  const float* w4 = (const float*)d_in[7];
  const float* b4 = (const float*)d_in[8];
  const float* w5 = (const float*)d_in[9];
  const float* b5 = (const float*)d_in[10];
  float* out = (float*)d_out;

  dim3 grid(65536 / 64);
  dim3 block(256);
  const bool packed = ws_size >= (size_t)(372 * 1024);
  if (packed) {
    pack_kernel<<<372, 64, 0, stream>>>(w1, w2, w3, w4, w5, (char*)d_ws);
    mlp5_kernel<true><<<grid, block, 0, stream>>>(x, w1, b1, w2, b2, w3, b3, w4, b4,
                                                  w5, b5, (const char*)d_ws, out);
  } else {
    mlp5_kernel<false><<<grid, block, 0, stream>>>(x, w1, b1, w2, b2, w3, b3, w4, b4,
                                                   w5, b5, nullptr, out);
  }
}

// Round 4
// 76.152 us; speedup vs baseline: 1.0329x; 1.0329x over previous
//
#include <hip/hip_runtime.h>
#include <hip/hip_bf16.h>
#include <stdint.h>

typedef __attribute__((ext_vector_type(4))) float f32x4;
typedef __attribute__((ext_vector_type(4))) unsigned int u32x4;
typedef __attribute__((ext_vector_type(8))) short short8;

#define MFMA16(a, b, c) __builtin_amdgcn_mfma_f32_16x16x32_bf16((a), (b), (c), 0, 0, 0)

__device__ __forceinline__ uint16_t f2bf(float f) {
  __hip_bfloat16 h = __float2bfloat16(f);
  return __builtin_bit_cast(uint16_t, h);
}

// v_rcp_f32-based sigmoid: rcp rel-err ~1ulp << bf16 rounding of every consumer.
__device__ __forceinline__ float fast_sigmoid(float v) {
  return __builtin_amdgcn_rcpf(1.f + __expf(-v));
}

__device__ __forceinline__ short8 cvt8(f32x4 a, f32x4 b) {
  short8 r;
  r[0] = (short)f2bf(a[0]); r[1] = (short)f2bf(a[1]);
  r[2] = (short)f2bf(a[2]); r[3] = (short)f2bf(a[3]);
  r[4] = (short)f2bf(b[0]); r[5] = (short)f2bf(b[1]);
  r[6] = (short)f2bf(b[2]); r[7] = (short)f2bf(b[3]);
  return r;
}

// XOR-swizzled byte offset into row-major [rows][RB bytes] LDS tile (16B slots).
template <int RB>
__device__ __forceinline__ int swzoff(int row, int bcol) {
  constexpr int SLM = (((RB / 16) < 8 ? (RB / 16) : 8)) - 1;
  return row * RB + (bcol ^ ((row & SLM) << 4));
}

// A-fragment (16x32 bf16) from swizzled bf16 LDS tile.
template <int RB>
__device__ __forceinline__ short8 lds_a(const uint16_t* buf, int row0, int k0, int lane) {
  int r = row0 + (lane & 15);
  int bcol = (k0 + ((lane >> 4) << 3)) * 2;
  u32x4 raw = *(const u32x4*)((const char*)buf + swzoff<RB>(r, bcol));
  return __builtin_bit_cast(short8, raw);
}

// A-fragment (16x32 bf16) from the 144B-pitched K=64 staging chunk.
// pitch 144 = 9*16B: bank-group (9r+s)%8 = (r+s)%8 -> 16 rows at fixed slot
// spread evenly over all 8 groups (2 lanes/group = free). No XOR needed.
__device__ __forceinline__ short8 lds_a144(const char* sb, int row0, int kk, int lane) {
  int r = row0 + (lane & 15);
  return *(const short8*)(sb + r * 144 + ((kk * 4 + (lane >> 4)) << 4));
}

// Fragment from row-major fp32 M[ld] (coalesced 16-row pattern)
__device__ __forceinline__ short8 load_frag_f32(const float* M, int ld, int r0, int k0, int lane) {
  const float* p = M + (size_t)(r0 + (lane & 15)) * ld + (k0 + ((lane >> 4) << 3));
  f32x4 a = *(const f32x4*)p;
  f32x4 b = *(const f32x4*)(p + 4);
  return cvt8(a, b);
}

// Packed-path B-fragment: one coalesced 16B load from pre-packed d_ws
__device__ __forceinline__ short8 load_b_pk(const char* base, int f, int lane) {
  u32x4 raw = *(const u32x4*)(base + (((size_t)f * 64 + lane) << 4));
  return __builtin_bit_cast(short8, raw);
}

template <bool P>
__device__ __forceinline__ short8 bfrag(const char* wp, const float* W, int K,
                                        int f0, int ntg, int KT, int kt, int lane) {
  if constexpr (P) {
    return load_b_pk(wp, f0 + ntg * KT + kt, lane);
  } else {
    return load_frag_f32(W, K, ntg * 16, kt * 32, lane);
  }
}

// ---- weight pre-pack: 372 fragments x (64 lanes x 16B) = 372 KB in d_ws ----
__global__ void pack_kernel(const float* __restrict__ w1, const float* __restrict__ w2,
                            const float* __restrict__ w3, const float* __restrict__ w4,
                            const float* __restrict__ w5, char* __restrict__ ws) {
  int b = blockIdx.x, lane = threadIdx.x;
  const float* W;
  int K, f0;
  if (b < 256)      { W = w1; K = 512; f0 = 0; }
  else if (b < 320) { W = w2; K = 256; f0 = 256; }
  else if (b < 336) { W = w3; K = 128; f0 = 320; }
  else if (b < 340) { W = w4; K = 64;  f0 = 336; }
  else              { W = w5; K = 32;  f0 = 340; }
  int f = b - f0;
  int KT = K / 32;
  int nt = f / KT, kt = f % KT;
  short8 r = load_frag_f32(W, K, nt * 16, kt * 32, lane);
  *(u32x4*)(ws + (((size_t)b * 64 + lane) << 4)) = __builtin_bit_cast(u32x4, r);
}

// Non-draining chunk barrier: drain LDS ops only; VMEM prefetches stay in flight.
// sched_barrier(0) fences instruction motion across the barrier (rule #18).
#define CHUNK_BAR()                                           \
  asm volatile("s_waitcnt lgkmcnt(0)" ::: "memory");          \
  __builtin_amdgcn_s_barrier();                               \
  __builtin_amdgcn_sched_barrier(0);

// One L1 K=64 chunk (8 total -> half the barriers of the K=32 scheme).
// Register-carried pipeline; compiler derives all vmcnt waits:
//   chunk c x-rows: global->rA[c&1] at step c-2; cvt+ds_write at step c-1;
//   consumed as 2 half-chunks (4 ds_read_b128 + 16 MFMA each) at step c.
//   B frags: half-chunk ping-pong; B(h) reloaded with B(h+2) right after its
//   last MFMA -> issue-to-use ~1 full step, never on the critical path.
#define KSTEP64(C)                                                            \
  {                                                                           \
    CHUNK_BAR();                                                              \
    if ((C) + 2 < 8) {                                                        \
      const float* p = xrow + ((C) + 2) * 64;                                 \
      rA[(C) & 1][0] = *(const f32x4*)p;                                      \
      rA[(C) & 1][1] = *(const f32x4*)(p + 4);                                \
      rA[(C) & 1][2] = *(const f32x4*)(p + 32);                               \
      rA[(C) & 1][3] = *(const f32x4*)(p + 36);                               \
    }                                                                         \
    if ((C) + 1 < 8) {                                                        \
      short8 wv0 = cvt8(rA[((C) + 1) & 1][0], rA[((C) + 1) & 1][1]);          \
      short8 wv1 = cvt8(rA[((C) + 1) & 1][2], rA[((C) + 1) & 1][3]);          \
      char* wb = sring + (((C) + 1) & 1) * 9216 + swb;                        \
      *(short8*)(wb) = wv0;                                                   \
      *(short8*)(wb + 64) = wv1;                                              \
    }                                                                         \
    const char* sc = sring + ((C) & 1) * 9216;                                \
    _Pragma("unroll") for (int m = 0; m < 4; ++m) {                           \
      short8 a = lds_a144(sc, m * 16, 0, lane);                               \
      _Pragma("unroll") for (int nt = 0; nt < 4; ++nt)                        \
          acc[m][nt] = MFMA16(a, bfr[0][nt], acc[m][nt]);                     \
    }                                                                         \
    if (2 * (C) + 2 < 16) {                                                   \
      _Pragma("unroll") for (int nt = 0; nt < 4; ++nt)                        \
          bfr[0][nt] =                                                        \
              bfrag<P>(wp, w1, 512, 0, wid * 4 + nt, 16, 2 * (C) + 2, lane);  \
    }                                                                         \
    _Pragma("unroll") for (int m = 0; m < 4; ++m) {                           \
      short8 a = lds_a144(sc, m * 16, 1, lane);                               \
      _Pragma("unroll") for (int nt = 0; nt < 4; ++nt)                        \
          acc[m][nt] = MFMA16(a, bfr[1][nt], acc[m][nt]);                     \
    }                                                                         \
    if (2 * (C) + 3 < 16) {                                                   \
      _Pragma("unroll") for (int nt = 0; nt < 4; ++nt)                        \
          bfr[1][nt] =                                                        \
              bfrag<P>(wp, w1, 512, 0, wid * 4 + nt, 16, 2 * (C) + 3, lane);  \
    }                                                                         \
  }

// 64 rows/block, 256 threads, 32KB arena, (256,3): VGPR cap 168 (no spill;
// (256,4)'s 128-cap spilled ~100MB scratch in round 1).
template <bool P>
__global__ __launch_bounds__(256, 3) void mlp5_kernel(
    const float* __restrict__ x,
    const float* __restrict__ w1, const float* __restrict__ b1,
    const float* __restrict__ w2, const float* __restrict__ b2,
    const float* __restrict__ w3, const float* __restrict__ b3,
    const float* __restrict__ w4, const float* __restrict__ b4,
    const float* __restrict__ w5, const float* __restrict__ b5,
    const char* __restrict__ wp, float* __restrict__ out) {
  // Arena 32KB (every overlay is protected by an existing barrier):
  //   L1: S ring [0,18432) = 2 x 9216B bf16 K=64 chunks (144B pitch, reg-staged)
  //   L1 epilogue (after syncthreads): H1 [0,32K) overlays ring
  //   L2: H1 in; H2 [0,16K) out (after the barrier following last H1 read)
  //   L3: H2 in, H3 [16K,24K) out
  //   L4: H3 in, H4 [24K,28K) out
  //   L5: H4 in
  __shared__ __align__(16) char smem[32 * 1024];
  uint16_t* H1 = (uint16_t*)smem;                // [64][256] bf16, RB=512
  uint16_t* H2 = (uint16_t*)smem;                // [64][128] bf16, RB=256
  uint16_t* H3 = (uint16_t*)(smem + 16 * 1024);  // [64][64]  bf16, RB=128
  uint16_t* H4 = (uint16_t*)(smem + 24 * 1024);  // [64][32]  bf16, RB=64

  const int tid = threadIdx.x;
  const int lane = tid & 63;
  const int wid = tid >> 6;
  const int row0 = blockIdx.x * 64;
  const int lr = (lane >> 4) << 2;
  const int lc = lane & 15;

  // in_size = count_nonzero(x[0])
  int in_size = 0;
#pragma unroll
  for (int j = 0; j < 8; ++j) {
    float v = x[j * 64 + lane];
    in_size += (int)__popcll(__ballot(v != 0.f));
  }

  // ---- Layer 1: x[64x512] @ w1[256x512]^T -> h1[64x256]
  // Each wave stages its own 16 rows: global->reg (4 dwordx4/chunk), cvt once,
  // 2x ds_write_b128 into 144B-pitch chunk. Consumers: 8 ds_read_b128/chunk.
  char* sring = smem;
  const float* xrow =
      x + (size_t)(row0 + wid * 16 + (lane & 15)) * 512 + ((lane >> 4) << 3);
  const int swb = (wid * 16 + (lane & 15)) * 144 + ((lane >> 4) << 4);

  f32x4 acc[4][4];
#pragma unroll
  for (int m = 0; m < 4; ++m)
#pragma unroll
    for (int n = 0; n < 4; ++n) acc[m][n] = (f32x4){0.f, 0.f, 0.f, 0.f};

  f32x4 rA[2][4];
  short8 bfr[2][4];
  // Prologue: chunk0 -> rA[0], chunk1 -> rA[1], B(kt=0)->bfr[0], B(kt=1)->bfr[1];
  // cvt chunk0 -> LDS slot0 (compiler waits only chunk0's loads).
  rA[0][0] = *(const f32x4*)(xrow + 0);
  rA[0][1] = *(const f32x4*)(xrow + 4);
  rA[0][2] = *(const f32x4*)(xrow + 32);
  rA[0][3] = *(const f32x4*)(xrow + 36);
  rA[1][0] = *(const f32x4*)(xrow + 64);
  rA[1][1] = *(const f32x4*)(xrow + 68);
  rA[1][2] = *(const f32x4*)(xrow + 96);
  rA[1][3] = *(const f32x4*)(xrow + 100);
#pragma unroll
  for (int nt = 0; nt < 4; ++nt)
    bfr[0][nt] = bfrag<P>(wp, w1, 512, 0, wid * 4 + nt, 16, 0, lane);
#pragma unroll
  for (int nt = 0; nt < 4; ++nt)
    bfr[1][nt] = bfrag<P>(wp, w1, 512, 0, wid * 4 + nt, 16, 1, lane);
  {
    short8 wv0 = cvt8(rA[0][0], rA[0][1]);
    short8 wv1 = cvt8(rA[0][2], rA[0][3]);
    *(short8*)(sring + swb) = wv0;
    *(short8*)(sring + swb + 64) = wv1;
  }

  KSTEP64(0) KSTEP64(1) KSTEP64(2) KSTEP64(3)
  KSTEP64(4) KSTEP64(5) KSTEP64(6) KSTEP64(7)

  // Hoist L2 weights + L1 bias (latency hides under barrier + epilogue VALU)
  short8 bfr2[2][8];
#pragma unroll
  for (int n = 0; n < 2; ++n)
#pragma unroll
    for (int kt = 0; kt < 8; ++kt)
      bfr2[n][kt] = bfrag<P>(wp, w2, 256, 256, wid * 2 + n, 8, kt, lane);
  float bv1[4];
#pragma unroll
  for (int n = 0; n < 4; ++n) bv1[n] = b1[wid * 64 + n * 16 + lc];

  __syncthreads();  // all S-ring reads done before H1 overlays [0,32K)

  // L1 epilogue: bias + sigmoid -> H1
#pragma unroll
  for (int n = 0; n < 4; ++n) {
    const int ncol = wid * 64 + n * 16;
#pragma unroll
    for (int m = 0; m < 4; ++m)
#pragma unroll
      for (int i = 0; i < 4; ++i) {
        float v = fast_sigmoid(acc[m][n][i] + bv1[n]);
        *(uint16_t*)((char*)H1 + swzoff<512>(m * 16 + lr + i, (ncol + lc) * 2)) = f2bf(v);
      }
  }
  __syncthreads();

  // ---- Layer 2: h1[64x256] -> h2[64x128]; wave cols wid*32 (2 nt), 4 mt, KT=8
  {
    f32x4 acc2[4][2];
#pragma unroll
    for (int m = 0; m < 4; ++m)
#pragma unroll
      for (int n = 0; n < 2; ++n) acc2[m][n] = (f32x4){0.f, 0.f, 0.f, 0.f};
#pragma unroll
    for (int m = 0; m < 4; ++m) {
#pragma unroll
      for (int kt = 0; kt < 8; ++kt) {
        short8 afr = lds_a<512>(H1, m * 16, kt * 32, lane);
        acc2[m][0] = MFMA16(afr, bfr2[0][kt], acc2[m][0]);
        acc2[m][1] = MFMA16(afr, bfr2[1][kt], acc2[m][1]);
      }
    }
    // Hoist L3 weights + L2 bias
    short8 bfr3[4];
#pragma unroll
    for (int kt = 0; kt < 4; ++kt)
      bfr3[kt] = bfrag<P>(wp, w3, 128, 320, wid, 4, kt, lane);
    float bv2[2];
#pragma unroll
    for (int n = 0; n < 2; ++n) bv2[n] = b2[wid * 32 + n * 16 + lc];
    __syncthreads();  // REQUIRED: last H1 read done before H2 overlays [0,16K)
#pragma unroll
    for (int n = 0; n < 2; ++n) {
      const int ncol = wid * 32 + n * 16;
#pragma unroll
      for (int m = 0; m < 4; ++m)
#pragma unroll
        for (int i = 0; i < 4; ++i) {
          float v = fast_sigmoid(acc2[m][n][i] + bv2[n]);
          *(uint16_t*)((char*)H2 + swzoff<256>(m * 16 + lr + i, (ncol + lc) * 2)) = f2bf(v);
        }
    }
    __syncthreads();

    // ---- Layer 3: h2[64x128] -> h3[64x64]; wave col-tile wid (1 nt), 4 mt, KT=4
    f32x4 acc3[4];
#pragma unroll
    for (int m = 0; m < 4; ++m) acc3[m] = (f32x4){0.f, 0.f, 0.f, 0.f};
#pragma unroll
    for (int m = 0; m < 4; ++m)
#pragma unroll
      for (int kt = 0; kt < 4; ++kt) {
        short8 afr = lds_a<256>(H2, m * 16, kt * 32, lane);
        acc3[m] = MFMA16(afr, bfr3[kt], acc3[m]);
      }
    // Hoist L4 weights + L3 bias
    short8 bfr4[2];
#pragma unroll
    for (int kt = 0; kt < 2; ++kt)
      bfr4[kt] = bfrag<P>(wp, w4, 64, 336, wid & 1, 2, kt, lane);
    const float bv3 = b3[wid * 16 + lc];
    {
#pragma unroll
      for (int m = 0; m < 4; ++m)
#pragma unroll
        for (int i = 0; i < 4; ++i) {
          float v = fast_sigmoid(acc3[m][i] + bv3);
          *(uint16_t*)((char*)H3 + swzoff<128>(m * 16 + lr + i, (wid * 16 + lc) * 2)) = f2bf(v);
        }
    }
    __syncthreads();

    // ---- Layer 4: h3[64x64] -> h4[64x32]; waves 2x2: rows wm*32 (2 mt), col wn*16, KT=2
    const int wm = wid >> 1, wn = wid & 1;
    f32x4 acc4[2];
#pragma unroll
    for (int mt = 0; mt < 2; ++mt) acc4[mt] = (f32x4){0.f, 0.f, 0.f, 0.f};
#pragma unroll
    for (int mt = 0; mt < 2; ++mt)
#pragma unroll
      for (int kt = 0; kt < 2; ++kt) {
        short8 afr = lds_a<128>(H3, wm * 32 + mt * 16, kt * 32, lane);
        acc4[mt] = MFMA16(afr, bfr4[kt], acc4[mt]);
      }
    // Hoist L5 weights + L4/L5 bias
    short8 bfr5[8];
#pragma unroll
    for (int nt = 0; nt < 8; ++nt)
      bfr5[nt] = bfrag<P>(wp, w5, 32, 340, wid * 8 + nt, 1, 0, lane);
    const float bv4 = b4[wn * 16 + lc];
    float bv5[8];
#pragma unroll
    for (int nt = 0; nt < 8; ++nt) bv5[nt] = b5[wid * 128 + nt * 16 + lc];
    {
#pragma unroll
      for (int mt = 0; mt < 2; ++mt)
#pragma unroll
        for (int i = 0; i < 4; ++i) {
          float v = fast_sigmoid(acc4[mt][i] + bv4);
          *(uint16_t*)((char*)H4 + swzoff<64>(wm * 32 + mt * 16 + lr + i, (wn * 16 + lc) * 2)) = f2bf(v);
        }
    }
    __syncthreads();

    // ---- Layer 5: h4[64x32] -> out[64x512]; wave cols wid*128 (8 nt), 4 mt, KT=1
#pragma unroll
    for (int m = 0; m < 4; ++m) {
      short8 afr = lds_a<64>(H4, m * 16, 0, lane);
#pragma unroll
      for (int nt = 0; nt < 8; ++nt) {
        f32x4 av = MFMA16(afr, bfr5[nt], ((f32x4){0.f, 0.f, 0.f, 0.f}));
        const int col = wid * 128 + nt * 16 + lc;
        const bool keep = col < in_size;
#pragma unroll
        for (int i = 0; i < 4; ++i) {
          float v = keep ? (av[i] + bv5[nt]) : 0.f;
          out[(size_t)(row0 + m * 16 + lr + i) * 512 + col] = v;
        }
      }
    }
  }
}

extern "C" void kernel_launch(void* const* d_in, const int* in_sizes, int n_in,
                              void* d_out, int out_size, void* d_ws, size_t ws_size,
                              hipStream_t stream) {
  const float* x  = (const float*)d_in[0];
  const float* w1 = (const float*)d_in[1];
  const float* b1 = (const float*)d_in[2];
  const float* w2 = (const float*)d_in[3];
  const float* b2 = (const float*)d_in[4];
  const float* w3 = (const float*)d_in[5];
  const float* b3 = (const float*)d_in[6];
  const float* w4 = (const float*)d_in[7];
  const float* b4 = (const float*)d_in[8];
  const float* w5 = (const float*)d_in[9];
  const float* b5 = (const float*)d_in[10];
  float* out = (float*)d_out;

  dim3 grid(65536 / 64);
  dim3 block(256);
  const bool packed = ws_size >= (size_t)(372 * 1024);
  if (packed) {
    pack_kernel<<<372, 64, 0, stream>>>(w1, w2, w3, w4, w5, (char*)d_ws);
    mlp5_kernel<true><<<grid, block, 0, stream>>>(x, w1, b1, w2, b2, w3, b3, w4, b4,
                                                  w5, b5, (const char*)d_ws, out);
  } else {
    mlp5_kernel<false><<<grid, block, 0, stream>>>(x, w1, b1, w2, b2, w3, b3, w4, b4,
                                                   w5, b5, nullptr, out);
  }
}

// Round 5
// 75.286 us; speedup vs baseline: 1.0448x; 1.0115x over previous
//
#include <hip/hip_runtime.h>
#include <hip/hip_bf16.h>
#include <stdint.h>

typedef __attribute__((ext_vector_type(4))) float f32x4;
typedef __attribute__((ext_vector_type(4))) unsigned int u32x4;
typedef __attribute__((ext_vector_type(8))) short short8;

#define MFMA16(a, b, c) __builtin_amdgcn_mfma_f32_16x16x32_bf16((a), (b), (c), 0, 0, 0)

__device__ __forceinline__ uint16_t f2bf(float f) {
  __hip_bfloat16 h = __float2bfloat16(f);
  return __builtin_bit_cast(uint16_t, h);
}

// v_rcp_f32-based sigmoid: rcp rel-err ~1ulp << bf16 rounding of every consumer.
__device__ __forceinline__ float fast_sigmoid(float v) {
  return __builtin_amdgcn_rcpf(1.f + __expf(-v));
}

__device__ __forceinline__ short8 cvt8(f32x4 a, f32x4 b) {
  short8 r;
  r[0] = (short)f2bf(a[0]); r[1] = (short)f2bf(a[1]);
  r[2] = (short)f2bf(a[2]); r[3] = (short)f2bf(a[3]);
  r[4] = (short)f2bf(b[0]); r[5] = (short)f2bf(b[1]);
  r[6] = (short)f2bf(b[2]); r[7] = (short)f2bf(b[3]);
  return r;
}

// XOR-swizzled byte offset into row-major [rows][RB bytes] LDS tile (16B slots).
template <int RB>
__device__ __forceinline__ int swzoff(int row, int bcol) {
  constexpr int SLM = (((RB / 16) < 8 ? (RB / 16) : 8)) - 1;
  return row * RB + (bcol ^ ((row & SLM) << 4));
}

// A-fragment (16x32 bf16) from swizzled bf16 LDS tile.
template <int RB>
__device__ __forceinline__ short8 lds_a(const uint16_t* buf, int row0, int k0, int lane) {
  int r = row0 + (lane & 15);
  int bcol = (k0 + ((lane >> 4) << 3)) * 2;
  u32x4 raw = *(const u32x4*)((const char*)buf + swzoff<RB>(r, bcol));
  return __builtin_bit_cast(short8, raw);
}

// A-fragment (16x32 bf16) from the 144B-pitched K=64 staging chunk.
// pitch 144 = 9*16B: bank-group (9r+s)%8 = (r+s)%8 -> 16 rows at fixed slot
// spread evenly over all 8 groups (2 lanes/group = free). No XOR needed.
__device__ __forceinline__ short8 lds_a144(const char* sb, int row0, int kk, int lane) {
  int r = row0 + (lane & 15);
  return *(const short8*)(sb + r * 144 + ((kk * 4 + (lane >> 4)) << 4));
}

// Fragment from row-major fp32 M[ld] (coalesced 16-row pattern)
__device__ __forceinline__ short8 load_frag_f32(const float* M, int ld, int r0, int k0, int lane) {
  const float* p = M + (size_t)(r0 + (lane & 15)) * ld + (k0 + ((lane >> 4) << 3));
  f32x4 a = *(const f32x4*)p;
  f32x4 b = *(const f32x4*)(p + 4);
  return cvt8(a, b);
}

// Packed-path B-fragment: one coalesced 16B load from pre-packed d_ws
__device__ __forceinline__ short8 load_b_pk(const char* base, int f, int lane) {
  u32x4 raw = *(const u32x4*)(base + (((size_t)f * 64 + lane) << 4));
  return __builtin_bit_cast(short8, raw);
}

template <bool P>
__device__ __forceinline__ short8 bfrag(const char* wp, const float* W, int K,
                                        int f0, int ntg, int KT, int kt, int lane) {
  if constexpr (P) {
    return load_b_pk(wp, f0 + ntg * KT + kt, lane);
  } else {
    return load_frag_f32(W, K, ntg * 16, kt * 32, lane);
  }
}

// ---- weight pre-pack: 372 fragments x (64 lanes x 16B) = 372 KB in d_ws ----
__global__ void pack_kernel(const float* __restrict__ w1, const float* __restrict__ w2,
                            const float* __restrict__ w3, const float* __restrict__ w4,
                            const float* __restrict__ w5, char* __restrict__ ws) {
  int b = blockIdx.x, lane = threadIdx.x;
  const float* W;
  int K, f0;
  if (b < 256)      { W = w1; K = 512; f0 = 0; }
  else if (b < 320) { W = w2; K = 256; f0 = 256; }
  else if (b < 336) { W = w3; K = 128; f0 = 320; }
  else if (b < 340) { W = w4; K = 64;  f0 = 336; }
  else              { W = w5; K = 32;  f0 = 340; }
  int f = b - f0;
  int KT = K / 32;
  int nt = f / KT, kt = f % KT;
  short8 r = load_frag_f32(W, K, nt * 16, kt * 32, lane);
  *(u32x4*)(ws + (((size_t)b * 64 + lane) << 4)) = __builtin_bit_cast(u32x4, r);
}

// Non-draining chunk barrier: drain LDS ops only; VMEM prefetches stay in flight.
// sched_barrier(0) fences instruction motion across the barrier (rule #18).
#define CHUNK_BAR()                                           \
  asm volatile("s_waitcnt lgkmcnt(0)" ::: "memory");          \
  __builtin_amdgcn_s_barrier();                               \
  __builtin_amdgcn_sched_barrier(0);

// One L1 K=64 chunk (8 total). 32-row block: each lane stages 8 cols of one row
// (row = wid*8 + lane>>3), one short8 ds_write per chunk. Register-carried
// pipeline; compiler derives all vmcnt waits:
//   chunk c x: global->rA[c&1] at step c-2; cvt+ds_write at step c-1;
//   consumed as 2 half-chunks (2 ds_read_b128 + 8 MFMA each) at step c.
//   B frags: half-chunk ping-pong, reloaded right after last use.
#define KSTEP64(C)                                                            \
  {                                                                           \
    CHUNK_BAR();                                                              \
    if ((C) + 2 < 8) {                                                        \
      const float* p = xrow + ((C) + 2) * 64;                                 \
      rA[(C) & 1][0] = *(const f32x4*)p;                                      \
      rA[(C) & 1][1] = *(const f32x4*)(p + 4);                                \
    }                                                                         \
    if ((C) + 1 < 8) {                                                        \
      short8 wv = cvt8(rA[((C) + 1) & 1][0], rA[((C) + 1) & 1][1]);           \
      *(short8*)(sring + (((C) + 1) & 1) * 4608 + swb) = wv;                  \
    }                                                                         \
    const char* sc = sring + ((C) & 1) * 4608;                                \
    _Pragma("unroll") for (int m = 0; m < 2; ++m) {                           \
      short8 a = lds_a144(sc, m * 16, 0, lane);                               \
      _Pragma("unroll") for (int nt = 0; nt < 4; ++nt)                        \
          acc[m][nt] = MFMA16(a, bfr[0][nt], acc[m][nt]);                     \
    }                                                                         \
    if (2 * (C) + 2 < 16) {                                                   \
      _Pragma("unroll") for (int nt = 0; nt < 4; ++nt)                        \
          bfr[0][nt] =                                                        \
              bfrag<P>(wp, w1, 512, 0, wid * 4 + nt, 16, 2 * (C) + 2, lane);  \
    }                                                                         \
    _Pragma("unroll") for (int m = 0; m < 2; ++m) {                           \
      short8 a = lds_a144(sc, m * 16, 1, lane);                               \
      _Pragma("unroll") for (int nt = 0; nt < 4; ++nt)                        \
          acc[m][nt] = MFMA16(a, bfr[1][nt], acc[m][nt]);                     \
    }                                                                         \
    if (2 * (C) + 3 < 16) {                                                   \
      _Pragma("unroll") for (int nt = 0; nt < 4; ++nt)                        \
          bfr[1][nt] =                                                        \
              bfrag<P>(wp, w1, 512, 0, wid * 4 + nt, 16, 2 * (C) + 3, lane);  \
    }                                                                         \
  }

// 32 rows/block, 256 threads, 16KB arena, 2048 blocks -> 4 resident blocks/CU
// (wave-limited) x 2 generations: gen-2's read/MFMA L1 overlaps gen-1's
// VALU/write tail, halving the lockstep-cohort stalls of the 1024x64 layout.
// (256,3): VGPR cap 168 (round 1 showed the 128-cap spills ~100MB scratch).
template <bool P>
__global__ __launch_bounds__(256, 3) void mlp5_kernel(
    const float* __restrict__ x,
    const float* __restrict__ w1, const float* __restrict__ b1,
    const float* __restrict__ w2, const float* __restrict__ b2,
    const float* __restrict__ w3, const float* __restrict__ b3,
    const float* __restrict__ w4, const float* __restrict__ b4,
    const float* __restrict__ w5, const float* __restrict__ b5,
    const char* __restrict__ wp, float* __restrict__ out) {
  // Arena 16KB (every overlay is protected by an existing barrier):
  //   L1: S ring [0,9216) = 2 x 4608B bf16 K=64 chunks (144B pitch, reg-staged)
  //   L1 epilogue (after syncthreads): H1 [0,16K) overlays ring
  //   L2: H1 in; H2 [0,8K) out (after the barrier following last H1 read)
  //   L3: H2 in, H3 [8K,12K) out
  //   L4: H3 in, H4 [12K,14K) out
  //   L5: H4 in
  __shared__ __align__(16) char smem[16 * 1024];
  uint16_t* H1 = (uint16_t*)smem;                // [32][256] bf16, RB=512
  uint16_t* H2 = (uint16_t*)smem;                // [32][128] bf16, RB=256
  uint16_t* H3 = (uint16_t*)(smem + 8 * 1024);   // [32][64]  bf16, RB=128
  uint16_t* H4 = (uint16_t*)(smem + 12 * 1024);  // [32][32]  bf16, RB=64

  const int tid = threadIdx.x;
  const int lane = tid & 63;
  const int wid = tid >> 6;
  const int row0 = blockIdx.x * 32;
  const int lr = (lane >> 4) << 2;
  const int lc = lane & 15;

  // in_size = count_nonzero(x[0])
  int in_size = 0;
#pragma unroll
  for (int j = 0; j < 8; ++j) {
    float v = x[j * 64 + lane];
    in_size += (int)__popcll(__ballot(v != 0.f));
  }

  // ---- Layer 1: x[32x512] @ w1[256x512]^T -> h1[32x256]
  // Each lane stages 8 cols of row (wid*8 + lane>>3): global 2x dwordx4, cvt
  // once, one ds_write_b128 into 144B-pitch chunk. 4 ds_read_b128/wave/chunk.
  char* sring = smem;
  const float* xrow =
      x + (size_t)(row0 + wid * 8 + (lane >> 3)) * 512 + ((lane & 7) << 3);
  const int swb = (wid * 8 + (lane >> 3)) * 144 + ((lane & 7) << 4);

  f32x4 acc[2][4];
#pragma unroll
  for (int m = 0; m < 2; ++m)
#pragma unroll
    for (int n = 0; n < 4; ++n) acc[m][n] = (f32x4){0.f, 0.f, 0.f, 0.f};

  f32x4 rA[2][2];
  short8 bfr[2][4];
  // Prologue: chunk0 -> rA[0], chunk1 -> rA[1], B(kt=0)->bfr[0], B(kt=1)->bfr[1];
  // cvt chunk0 -> LDS slot0 (compiler waits only chunk0's loads).
  rA[0][0] = *(const f32x4*)(xrow + 0);
  rA[0][1] = *(const f32x4*)(xrow + 4);
  rA[1][0] = *(const f32x4*)(xrow + 64);
  rA[1][1] = *(const f32x4*)(xrow + 68);
#pragma unroll
  for (int nt = 0; nt < 4; ++nt)
    bfr[0][nt] = bfrag<P>(wp, w1, 512, 0, wid * 4 + nt, 16, 0, lane);
#pragma unroll
  for (int nt = 0; nt < 4; ++nt)
    bfr[1][nt] = bfrag<P>(wp, w1, 512, 0, wid * 4 + nt, 16, 1, lane);
  {
    short8 wv = cvt8(rA[0][0], rA[0][1]);
    *(short8*)(sring + swb) = wv;
  }

  KSTEP64(0) KSTEP64(1) KSTEP64(2) KSTEP64(3)
  KSTEP64(4) KSTEP64(5) KSTEP64(6) KSTEP64(7)

  // Hoist L2 weights + L1 bias (latency hides under barrier + epilogue VALU)
  short8 bfr2[2][8];
#pragma unroll
  for (int n = 0; n < 2; ++n)
#pragma unroll
    for (int kt = 0; kt < 8; ++kt)
      bfr2[n][kt] = bfrag<P>(wp, w2, 256, 256, wid * 2 + n, 8, kt, lane);
  float bv1[4];
#pragma unroll
  for (int n = 0; n < 4; ++n) bv1[n] = b1[wid * 64 + n * 16 + lc];

  __syncthreads();  // all S-ring reads done before H1 overlays [0,16K)

  // L1 epilogue: bias + sigmoid -> H1
#pragma unroll
  for (int n = 0; n < 4; ++n) {
    const int ncol = wid * 64 + n * 16;
#pragma unroll
    for (int m = 0; m < 2; ++m)
#pragma unroll
      for (int i = 0; i < 4; ++i) {
        float v = fast_sigmoid(acc[m][n][i] + bv1[n]);
        *(uint16_t*)((char*)H1 + swzoff<512>(m * 16 + lr + i, (ncol + lc) * 2)) = f2bf(v);
      }
  }
  __syncthreads();

  // ---- Layer 2: h1[32x256] -> h2[32x128]; wave cols wid*32 (2 nt), 2 mt, KT=8
  {
    f32x4 acc2[2][2];
#pragma unroll
    for (int m = 0; m < 2; ++m)
#pragma unroll
      for (int n = 0; n < 2; ++n) acc2[m][n] = (f32x4){0.f, 0.f, 0.f, 0.f};
#pragma unroll
    for (int m = 0; m < 2; ++m) {
#pragma unroll
      for (int kt = 0; kt < 8; ++kt) {
        short8 afr = lds_a<512>(H1, m * 16, kt * 32, lane);
        acc2[m][0] = MFMA16(afr, bfr2[0][kt], acc2[m][0]);
        acc2[m][1] = MFMA16(afr, bfr2[1][kt], acc2[m][1]);
      }
    }
    // Hoist L3 weights + L2 bias
    short8 bfr3[4];
#pragma unroll
    for (int kt = 0; kt < 4; ++kt)
      bfr3[kt] = bfrag<P>(wp, w3, 128, 320, wid, 4, kt, lane);
    float bv2[2];
#pragma unroll
    for (int n = 0; n < 2; ++n) bv2[n] = b2[wid * 32 + n * 16 + lc];
    __syncthreads();  // REQUIRED: last H1 read done before H2 overlays [0,8K)
#pragma unroll
    for (int n = 0; n < 2; ++n) {
      const int ncol = wid * 32 + n * 16;
#pragma unroll
      for (int m = 0; m < 2; ++m)
#pragma unroll
        for (int i = 0; i < 4; ++i) {
          float v = fast_sigmoid(acc2[m][n][i] + bv2[n]);
          *(uint16_t*)((char*)H2 + swzoff<256>(m * 16 + lr + i, (ncol + lc) * 2)) = f2bf(v);
        }
    }
    __syncthreads();

    // ---- Layer 3: h2[32x128] -> h3[32x64]; wave col-tile wid (1 nt), 2 mt, KT=4
    f32x4 acc3[2];
#pragma unroll
    for (int m = 0; m < 2; ++m) acc3[m] = (f32x4){0.f, 0.f, 0.f, 0.f};
#pragma unroll
    for (int m = 0; m < 2; ++m)
#pragma unroll
      for (int kt = 0; kt < 4; ++kt) {
        short8 afr = lds_a<256>(H2, m * 16, kt * 32, lane);
        acc3[m] = MFMA16(afr, bfr3[kt], acc3[m]);
      }
    // Hoist L4 weights + L3 bias
    short8 bfr4[2];
#pragma unroll
    for (int kt = 0; kt < 2; ++kt)
      bfr4[kt] = bfrag<P>(wp, w4, 64, 336, wid & 1, 2, kt, lane);
    const float bv3 = b3[wid * 16 + lc];
    // H3 [8K,12K) is disjoint from H2 [0,8K): no barrier needed before write
    {
#pragma unroll
      for (int m = 0; m < 2; ++m)
#pragma unroll
        for (int i = 0; i < 4; ++i) {
          float v = fast_sigmoid(acc3[m][i] + bv3);
          *(uint16_t*)((char*)H3 + swzoff<128>(m * 16 + lr + i, (wid * 16 + lc) * 2)) = f2bf(v);
        }
    }
    __syncthreads();

    // ---- Layer 4: h3[32x64] -> h4[32x32]; waves 2x2: rows wm*16 (1 mt), col wn*16, KT=2
    const int wm = wid >> 1, wn = wid & 1;
    f32x4 acc4 = (f32x4){0.f, 0.f, 0.f, 0.f};
#pragma unroll
    for (int kt = 0; kt < 2; ++kt) {
      short8 afr = lds_a<128>(H3, wm * 16, kt * 32, lane);
      acc4 = MFMA16(afr, bfr4[kt], acc4);
    }
    // Hoist L5 weights + L4/L5 bias
    short8 bfr5[8];
#pragma unroll
    for (int nt = 0; nt < 8; ++nt)
      bfr5[nt] = bfrag<P>(wp, w5, 32, 340, wid * 8 + nt, 1, 0, lane);
    const float bv4 = b4[wn * 16 + lc];
    float bv5[8];
#pragma unroll
    for (int nt = 0; nt < 8; ++nt) bv5[nt] = b5[wid * 128 + nt * 16 + lc];
    // H4 [12K,14K) disjoint from H3 reads: no barrier needed before write
    {
#pragma unroll
      for (int i = 0; i < 4; ++i) {
        float v = fast_sigmoid(acc4[i] + bv4);
        *(uint16_t*)((char*)H4 + swzoff<64>(wm * 16 + lr + i, (wn * 16 + lc) * 2)) = f2bf(v);
      }
    }
    __syncthreads();

    // ---- Layer 5: h4[32x32] -> out[32x512]; wave cols wid*128 (8 nt), 2 mt, KT=1
#pragma unroll
    for (int m = 0; m < 2; ++m) {
      short8 afr = lds_a<64>(H4, m * 16, 0, lane);
#pragma unroll
      for (int nt = 0; nt < 8; ++nt) {
        f32x4 av = MFMA16(afr, bfr5[nt], ((f32x4){0.f, 0.f, 0.f, 0.f}));
        const int col = wid * 128 + nt * 16 + lc;
        const bool keep = col < in_size;
#pragma unroll
        for (int i = 0; i < 4; ++i) {
          float v = keep ? (av[i] + bv5[nt]) : 0.f;
          out[(size_t)(row0 + m * 16 + lr + i) * 512 + col] = v;
        }
      }
    }
  }
}

extern "C" void kernel_launch(void* const* d_in, const int* in_sizes, int n_in,
                              void* d_out, int out_size, void* d_ws, size_t ws_size,
                              hipStream_t stream) {
  const float* x  = (const float*)d_in[0];
  const float* w1 = (const float*)d_in[1];
  const float* b1 = (const float*)d_in[2];
  const float* w2 = (const float*)d_in[3];
  const float* b2 = (const float*)d_in[4];
  const float* w3 = (const float*)d_in[5];
  const float* b3 = (const float*)d_in[6];
  const float* w4 = (const float*)d_in[7];
  const float* b4 = (const float*)d_in[8];
  const float* w5 = (const float*)d_in[9];
  const float* b5 = (const float*)d_in[10];
  float* out = (float*)d_out;

  dim3 grid(65536 / 32);
  dim3 block(256);
  const bool packed = ws_size >= (size_t)(372 * 1024);
  if (packed) {
    pack_kernel<<<372, 64, 0, stream>>>(w1, w2, w3, w4, w5, (char*)d_ws);
    mlp5_kernel<true><<<grid, block, 0, stream>>>(x, w1, b1, w2, b2, w3, b3, w4, b4,
                                                  w5, b5, (const char*)d_ws, out);
  } else {
    mlp5_kernel<false><<<grid, block, 0, stream>>>(x, w1, b1, w2, b2, w3, b3, w4, b4,
                                                   w5, b5, nullptr, out);
  }
}